// Round 9
// baseline (135.722 us; speedup 1.0000x reference)
//
#include <hip/hip_runtime.h>

// Problem constants (fixed shapes from the reference).
constexpr int B = 2, C = 320, H = 128, W = 240;
constexpr int G = 40, CPG = 8, MAXD = 48;
constexpr int HW = H * W;
constexpr int NROW = B * G * H;        // 10240 (b,g,h) rows
constexpr int ROWS_PER_BLOCK = 8;      // 8 waves/block, one row each, consecutive h
constexpr int W4 = W / 4;              // 60 float4 per channel row

typedef float f32x4 __attribute__((ext_vector_type(4)));

// Address-space-qualified void types for global_load_lds.
typedef const __attribute__((address_space(1))) void g_void;
typedef __attribute__((address_space(3))) void lds_void;

// out[b,g,d,h,x] = (1/CPG) * sum_k L[b, g*CPG+k, h, x] * R[b, g*CPG+k, h, x-d]  (x>=d, else 0)
//
// R9 = R7 with ONE change (clean A/B): cooperative stores are PLAIN cached
// stores instead of nontemporal. Mechanism under test: the 7.0 TB/s fill
// kernel uses plain stores — L2 writeback gives the memory controller a
// large bank-aware write-scheduling window, vs nt's per-line bypass. Loads
// stay nontemporal (read-once; don't evict pending write lines from L2).
// Everything else identical to R7 (117.7 us): 512 thr / 8 rows, gload_lds
// staging, single vmcnt(0) head, lgkm-only barriers, dense 7680B chunks.
__global__ __launch_bounds__(512) void gwc_volume_kernel(
    const float* __restrict__ left, const float* __restrict__ right,
    float* __restrict__ out)
{
    const int tid  = threadIdx.x;
    const int wv   = tid >> 6;   // wave id within block -> which row (0..7)
    const int lane = tid & 63;
    const int row  = blockIdx.x * ROWS_PER_BLOCK + wv;

    const int h  = row % H;
    const int h0 = h - wv;       // block's first h row (8 | H, never straddles (b,g))
    const int bg = row / H;
    const int g  = bg % G;
    const int b  = bg / G;

    // Staged right rows: 8 waves x 480 float4 = 61.4 KB (linear, gload_lds dest).
    __shared__ f32x4 sR4[ROWS_PER_BLOCK][CPG * W4];
    // Write-coalescing buffer for one dd-pair: [ddl][row][x4] = 15.4 KB.
    __shared__ f32x4 wb[2][ROWS_PER_BLOCK][W4];

    const size_t in_base = ((size_t)(b * C + g * CPG) * H + h) * (size_t)W;

    const int t = lane;                  // x-tile index, x = 4t..4t+3
    const bool active = (t < W4);        // lanes 60..63: staging + coop store only

    // ---- issue LEFT loads first (registers), so they fly with R staging ----
    f32x4 Lv[CPG];
    if (active) {
        #pragma unroll
        for (int k = 0; k < CPG; ++k)
            Lv[k] = __builtin_nontemporal_load(
                reinterpret_cast<const f32x4*>(left + in_base + (size_t)k * HW + 4 * t));
    }

    // ---- stage RIGHT row: direct HBM -> LDS, 8 x (64 lanes x 16 B) chunks ----
    #pragma unroll
    for (int i = 0; i < 8; ++i) {
        const int j = i * 64 + lane;     // float4 index: j = k*60 + x4
        if (j < CPG * W4) {
            const int k  = j / W4;
            const int x4 = j - k * W4;
            const float* src = right + in_base + (size_t)k * HW + 4 * x4;
            char* dst = (char*)&sR4[wv][0] + (size_t)i * 1024;
            __builtin_amdgcn_global_load_lds((g_void*)src, (lds_void*)dst, 16, 0, 0);
        }
    }

    // One drain for BOTH batches (L regs + LDS staging), then compute.
    asm volatile("s_waitcnt vmcnt(0)" ::: "memory");
    __builtin_amdgcn_sched_barrier(0);

    const f32x4* sr = &sR4[wv][0];
    const f32x4* wbflat = &wb[0][0][0];
    // Base (in floats) of the block's 8-row chunk in d-slice 0 of this (b,g).
    const size_t chunk00 = ((size_t)bg * MAXD * H + h0) * (size_t)W;

    // ---- 12 disparity groups of 4 ----
    #pragma unroll 1
    for (int dg = 0; dg < MAXD / 4; ++dg) {
        float acc[4][4];
        #pragma unroll
        for (int dd = 0; dd < 4; ++dd)
            #pragma unroll
            for (int xx = 0; xx < 4; ++xx) acc[dd][xx] = 0.f;

        if (active && t >= dg) {         // t < dg: whole tile in the zero wedge
            #pragma unroll
            for (int k = 0; k < CPG; ++k) {
                const int base = k * W4 + (t - dg);
                const f32x4 hi = sr[base];                   // R[A .. A+3]
                f32x4 lo;
                if (t > dg) lo = sr[base - 1];               // R[A-4 .. A-1]
                else        lo = (f32x4){0.f, 0.f, 0.f, 0.f}; // x<d -> zeros
                float win[8];
                win[0] = lo.x; win[1] = lo.y; win[2] = lo.z; win[3] = lo.w;
                win[4] = hi.x; win[5] = hi.y; win[6] = hi.z; win[7] = hi.w;
                // r-index = A + xx - dd -> win[4 + xx - dd]
                #pragma unroll
                for (int dd = 0; dd < 4; ++dd)
                    #pragma unroll
                    for (int xx = 0; xx < 4; ++xx)
                        acc[dd][xx] += Lv[k][xx] * win[4 + xx - dd];
            }
        }

        // ---- two dd-pair writeback phases through LDS ----
        #pragma unroll
        for (int phase = 0; phase < 2; ++phase) {
            if (active) {
                #pragma unroll
                for (int ddl = 0; ddl < 2; ++ddl) {
                    const int dd = phase * 2 + ddl;
                    f32x4 o;
                    o.x = acc[dd][0] * 0.125f;
                    o.y = acc[dd][1] * 0.125f;
                    o.z = acc[dd][2] * 0.125f;
                    o.w = acc[dd][3] * 0.125f;
                    wb[ddl][wv][t] = o;
                }
            }
            asm volatile("s_waitcnt lgkmcnt(0)" ::: "memory");
            __builtin_amdgcn_s_barrier();
            __builtin_amdgcn_sched_barrier(0);

            // Cooperative dense store: 960 f32x4 (2 slices x 8 rows x 960B),
            // tid-linear -> full 1024B-aligned 64-lane bursts. PLAIN stores:
            // let L2 aggregate and schedule the write stream.
            const int d_base = dg * 4 + phase * 2;
            const size_t cbase = chunk00 + (size_t)d_base * HW;  // floats
            {
                const int f   = tid;                 // 0..511
                const int ddl = f / 480;
                const int rem = f - ddl * 480;
                const f32x4 v = wbflat[f];
                *reinterpret_cast<f32x4*>(out + cbase + (size_t)ddl * HW + 4 * rem) = v;
            }
            if (tid < 960 - 512) {                   // second sweep: f = tid+512
                const int f   = tid + 512;           // 512..959 -> ddl=1
                const int rem = f - 480;
                const f32x4 v = wbflat[f];
                *reinterpret_cast<f32x4*>(out + cbase + (size_t)HW + 4 * rem) = v;
            }

            asm volatile("s_waitcnt lgkmcnt(0)" ::: "memory");
            __builtin_amdgcn_s_barrier();            // wb reusable next phase
            __builtin_amdgcn_sched_barrier(0);
        }
    }
}

extern "C" void kernel_launch(void* const* d_in, const int* in_sizes, int n_in,
                              void* d_out, int out_size, void* d_ws, size_t ws_size,
                              hipStream_t stream) {
    const float* left  = (const float*)d_in[0];
    const float* right = (const float*)d_in[1];
    float* out = (float*)d_out;

    dim3 grid(NROW / ROWS_PER_BLOCK);   // 1280 blocks
    dim3 block(512);                    // 8 waves, 8 consecutive h rows of one (b,g)
    hipLaunchKernelGGL(gwc_volume_kernel, grid, block, 0, stream,
                       left, right, out);
}

// Round 10
// 134.583 us; speedup vs baseline: 1.0085x; 1.0085x over previous
//
#include <hip/hip_runtime.h>

// Problem constants (fixed shapes from the reference).
constexpr int B = 2, C = 320, H = 128, W = 240;
constexpr int G = 40, CPG = 8, MAXD = 48;
constexpr int HW = H * W;
constexpr int NROW = B * G * H;        // 10240 (b,g,h) rows
constexpr int ROWS_PER_BLOCK = 16;     // 16 waves/block, one row each, consecutive h
constexpr int W4 = W / 4;              // 60 float4 per channel row

typedef float f32x4 __attribute__((ext_vector_type(4)));

// Address-space-qualified void types for global_load_lds.
typedef const __attribute__((address_space(1))) void g_void;
typedef __attribute__((address_space(3))) void lds_void;

// out[b,g,d,h,x] = (1/CPG) * sum_k L[b, g*CPG+k, h, x] * R[b, g*CPG+k, h, x-d]  (x>=d, else 0)
//
// R10 = R7 with ONE change: 16 rows/block (1024 threads) instead of 8.
// Mechanism: the store-chunk-size trend (960B scattered -> 7.7KB clustered
// -> 7.7KB dense coop all helped; 3.8KB hurt). This doubles the dense
// contiguous nt-store chunk per d-slice to 16 rows x 960B = 15.4KB.
// LDS = 122.9K staging + 30.7K wb = 153.6KB -> 1 block/CU, 16 waves/CU
// (same occupancy as R7). Everything else identical: nt loads, gload_lds
// staging, single vmcnt(0) head, lgkm-only barriers, nt coop stores.
__global__ __launch_bounds__(1024) void gwc_volume_kernel(
    const float* __restrict__ left, const float* __restrict__ right,
    float* __restrict__ out)
{
    const int tid  = threadIdx.x;
    const int wv   = tid >> 6;   // wave id within block -> which row (0..15)
    const int lane = tid & 63;
    const int row  = blockIdx.x * ROWS_PER_BLOCK + wv;

    const int h  = row % H;
    const int h0 = h - wv;       // block's first h row (16 | H, never straddles (b,g))
    const int bg = row / H;
    const int g  = bg % G;
    const int b  = bg / G;

    // Staged right rows: 16 waves x 480 float4 = 122.9 KB (linear, gload_lds dest).
    __shared__ f32x4 sR4[ROWS_PER_BLOCK][CPG * W4];
    // Write-coalescing buffer for one dd-pair: [ddl][row][x4] = 30.7 KB.
    __shared__ f32x4 wb[2][ROWS_PER_BLOCK][W4];

    const size_t in_base = ((size_t)(b * C + g * CPG) * H + h) * (size_t)W;

    const int t = lane;                  // x-tile index, x = 4t..4t+3
    const bool active = (t < W4);        // lanes 60..63: staging + coop store only

    // ---- issue LEFT loads first (registers), so they fly with R staging ----
    f32x4 Lv[CPG];
    if (active) {
        #pragma unroll
        for (int k = 0; k < CPG; ++k)
            Lv[k] = __builtin_nontemporal_load(
                reinterpret_cast<const f32x4*>(left + in_base + (size_t)k * HW + 4 * t));
    }

    // ---- stage RIGHT row: direct HBM -> LDS, 8 x (64 lanes x 16 B) chunks ----
    #pragma unroll
    for (int i = 0; i < 8; ++i) {
        const int j = i * 64 + lane;     // float4 index: j = k*60 + x4
        if (j < CPG * W4) {
            const int k  = j / W4;
            const int x4 = j - k * W4;
            const float* src = right + in_base + (size_t)k * HW + 4 * x4;
            char* dst = (char*)&sR4[wv][0] + (size_t)i * 1024;
            __builtin_amdgcn_global_load_lds((g_void*)src, (lds_void*)dst, 16, 0, 0);
        }
    }

    // One drain for BOTH batches (L regs + LDS staging), then compute.
    asm volatile("s_waitcnt vmcnt(0)" ::: "memory");
    __builtin_amdgcn_sched_barrier(0);

    const f32x4* sr = &sR4[wv][0];
    const f32x4* wbflat = &wb[0][0][0];
    // Base (in floats) of the block's 16-row chunk in d-slice 0 of this (b,g).
    const size_t chunk00 = ((size_t)bg * MAXD * H + h0) * (size_t)W;

    // ---- 12 disparity groups of 4 ----
    #pragma unroll 1
    for (int dg = 0; dg < MAXD / 4; ++dg) {
        float acc[4][4];
        #pragma unroll
        for (int dd = 0; dd < 4; ++dd)
            #pragma unroll
            for (int xx = 0; xx < 4; ++xx) acc[dd][xx] = 0.f;

        if (active && t >= dg) {         // t < dg: whole tile in the zero wedge
            #pragma unroll
            for (int k = 0; k < CPG; ++k) {
                const int base = k * W4 + (t - dg);
                const f32x4 hi = sr[base];                   // R[A .. A+3]
                f32x4 lo;
                if (t > dg) lo = sr[base - 1];               // R[A-4 .. A-1]
                else        lo = (f32x4){0.f, 0.f, 0.f, 0.f}; // x<d -> zeros
                float win[8];
                win[0] = lo.x; win[1] = lo.y; win[2] = lo.z; win[3] = lo.w;
                win[4] = hi.x; win[5] = hi.y; win[6] = hi.z; win[7] = hi.w;
                // r-index = A + xx - dd -> win[4 + xx - dd]
                #pragma unroll
                for (int dd = 0; dd < 4; ++dd)
                    #pragma unroll
                    for (int xx = 0; xx < 4; ++xx)
                        acc[dd][xx] += Lv[k][xx] * win[4 + xx - dd];
            }
        }

        // ---- two dd-pair writeback phases through LDS ----
        #pragma unroll
        for (int phase = 0; phase < 2; ++phase) {
            if (active) {
                #pragma unroll
                for (int ddl = 0; ddl < 2; ++ddl) {
                    const int dd = phase * 2 + ddl;
                    f32x4 o;
                    o.x = acc[dd][0] * 0.125f;
                    o.y = acc[dd][1] * 0.125f;
                    o.z = acc[dd][2] * 0.125f;
                    o.w = acc[dd][3] * 0.125f;
                    wb[ddl][wv][t] = o;
                }
            }
            asm volatile("s_waitcnt lgkmcnt(0)" ::: "memory");
            __builtin_amdgcn_s_barrier();
            __builtin_amdgcn_sched_barrier(0);

            // Cooperative dense store: 1920 f32x4 (2 slices x 16 rows x 960B),
            // tid-linear -> 15.4KB contiguous nt chunk per slice.
            const int d_base = dg * 4 + phase * 2;
            const size_t cbase = chunk00 + (size_t)d_base * HW;  // floats
            {
                const int f   = tid;                 // 0..1023
                const int ddl = f / 960;
                const int rem = f - ddl * 960;
                const f32x4 v = wbflat[f];
                __builtin_nontemporal_store(
                    v, reinterpret_cast<f32x4*>(out + cbase + (size_t)ddl * HW + 4 * rem));
            }
            if (tid < 1920 - 1024) {                 // second sweep: f = tid+1024
                const int f   = tid + 1024;          // 1024..1919 -> ddl=1
                const int rem = f - 960;
                const f32x4 v = wbflat[f];
                __builtin_nontemporal_store(
                    v, reinterpret_cast<f32x4*>(out + cbase + (size_t)HW + 4 * rem));
            }

            asm volatile("s_waitcnt lgkmcnt(0)" ::: "memory");
            __builtin_amdgcn_s_barrier();            // wb reusable next phase
            __builtin_amdgcn_sched_barrier(0);
        }
    }
}

extern "C" void kernel_launch(void* const* d_in, const int* in_sizes, int n_in,
                              void* d_out, int out_size, void* d_ws, size_t ws_size,
                              hipStream_t stream) {
    const float* left  = (const float*)d_in[0];
    const float* right = (const float*)d_in[1];
    float* out = (float*)d_out;

    dim3 grid(NROW / ROWS_PER_BLOCK);   // 640 blocks
    dim3 block(1024);                   // 16 waves, 16 consecutive h rows of one (b,g)
    hipLaunchKernelGGL(gwc_volume_kernel, grid, block, 0, stream,
                       left, right, out);
}

// Round 11
// 114.750 us; speedup vs baseline: 1.1828x; 1.1728x over previous
//
#include <hip/hip_runtime.h>

// Problem constants (fixed shapes from the reference).
constexpr int B = 2, C = 320, H = 128, W = 240;
constexpr int G = 40, CPG = 8, MAXD = 48;
constexpr int HW = H * W;
constexpr int NROW = B * G * H;        // 10240 (b,g,h) rows
constexpr int ROWS_PER_BLOCK = 8;      // 8 waves/block, one row each, consecutive h
constexpr int W4 = W / 4;              // 60 float4 per channel row
constexpr int NBLK = NROW / ROWS_PER_BLOCK;  // 1280
constexpr int NXCD = 8;                // 1280 % 8 == 0 -> simple swizzle bijective

typedef float f32x4 __attribute__((ext_vector_type(4)));

// Address-space-qualified void types for global_load_lds.
typedef const __attribute__((address_space(1))) void g_void;
typedef __attribute__((address_space(3))) void lds_void;

// out[b,g,d,h,x] = (1/CPG) * sum_k L[b, g*CPG+k, h, x] * R[b, g*CPG+k, h, x-d]  (x>=d, else 0)
//
// R11 = R7 (verified best, 117.7us) + ONE change: bijective XCD-aware
// blockIdx swizzle. Default dispatch round-robins consecutive blocks across
// 8 XCDs, scattering the 16 blocks that tile one bg's 123KB d-slice. With
// bid' = (bid%8)*160 + bid/8, each XCD owns 10 contiguous bg-groups: the 16
// blocks of a bg launch back-to-back on ONE XCD, run roughly in phase, and
// their per-phase nt stores tile full contiguous 123KB slice regions; each
// XCD's whole write footprint is one 59MB span instead of striped 472MB.
__global__ __launch_bounds__(512) void gwc_volume_kernel(
    const float* __restrict__ left, const float* __restrict__ right,
    float* __restrict__ out)
{
    const int tid  = threadIdx.x;
    const int wv   = tid >> 6;   // wave id within block -> which row (0..7)
    const int lane = tid & 63;

    // XCD swizzle: logical block id (bijective, 1280 = 8 * 160).
    const int bid  = blockIdx.x;
    const int lbid = (bid & (NXCD - 1)) * (NBLK / NXCD) + (bid >> 3);
    const int row  = lbid * ROWS_PER_BLOCK + wv;

    const int h  = row % H;
    const int h0 = h - wv;       // block's first h row (8 | H, never straddles (b,g))
    const int bg = row / H;
    const int g  = bg % G;
    const int b  = bg / G;

    // Staged right rows: 8 waves x 480 float4 = 61.4 KB (linear, gload_lds dest).
    __shared__ f32x4 sR4[ROWS_PER_BLOCK][CPG * W4];
    // Write-coalescing buffer for one dd-pair: [ddl][row][x4] = 15.4 KB.
    __shared__ f32x4 wb[2][ROWS_PER_BLOCK][W4];

    const size_t in_base = ((size_t)(b * C + g * CPG) * H + h) * (size_t)W;

    const int t = lane;                  // x-tile index, x = 4t..4t+3
    const bool active = (t < W4);        // lanes 60..63: staging + coop store only

    // ---- issue LEFT loads first (registers), so they fly with R staging ----
    f32x4 Lv[CPG];
    if (active) {
        #pragma unroll
        for (int k = 0; k < CPG; ++k)
            Lv[k] = __builtin_nontemporal_load(
                reinterpret_cast<const f32x4*>(left + in_base + (size_t)k * HW + 4 * t));
    }

    // ---- stage RIGHT row: direct HBM -> LDS, 8 x (64 lanes x 16 B) chunks ----
    #pragma unroll
    for (int i = 0; i < 8; ++i) {
        const int j = i * 64 + lane;     // float4 index: j = k*60 + x4
        if (j < CPG * W4) {
            const int k  = j / W4;
            const int x4 = j - k * W4;
            const float* src = right + in_base + (size_t)k * HW + 4 * x4;
            char* dst = (char*)&sR4[wv][0] + (size_t)i * 1024;
            __builtin_amdgcn_global_load_lds((g_void*)src, (lds_void*)dst, 16, 0, 0);
        }
    }

    // One drain for BOTH batches (L regs + LDS staging), then compute.
    asm volatile("s_waitcnt vmcnt(0)" ::: "memory");
    __builtin_amdgcn_sched_barrier(0);

    const f32x4* sr = &sR4[wv][0];
    const f32x4* wbflat = &wb[0][0][0];
    // Base (in floats) of the block's 8-row chunk in d-slice 0 of this (b,g).
    const size_t chunk00 = ((size_t)bg * MAXD * H + h0) * (size_t)W;

    // ---- 12 disparity groups of 4 ----
    #pragma unroll 1
    for (int dg = 0; dg < MAXD / 4; ++dg) {
        float acc[4][4];
        #pragma unroll
        for (int dd = 0; dd < 4; ++dd)
            #pragma unroll
            for (int xx = 0; xx < 4; ++xx) acc[dd][xx] = 0.f;

        if (active && t >= dg) {         // t < dg: whole tile in the zero wedge
            #pragma unroll
            for (int k = 0; k < CPG; ++k) {
                const int base = k * W4 + (t - dg);
                const f32x4 hi = sr[base];                   // R[A .. A+3]
                f32x4 lo;
                if (t > dg) lo = sr[base - 1];               // R[A-4 .. A-1]
                else        lo = (f32x4){0.f, 0.f, 0.f, 0.f}; // x<d -> zeros
                float win[8];
                win[0] = lo.x; win[1] = lo.y; win[2] = lo.z; win[3] = lo.w;
                win[4] = hi.x; win[5] = hi.y; win[6] = hi.z; win[7] = hi.w;
                // r-index = A + xx - dd -> win[4 + xx - dd]
                #pragma unroll
                for (int dd = 0; dd < 4; ++dd)
                    #pragma unroll
                    for (int xx = 0; xx < 4; ++xx)
                        acc[dd][xx] += Lv[k][xx] * win[4 + xx - dd];
            }
        }

        // ---- two dd-pair writeback phases through LDS ----
        #pragma unroll
        for (int phase = 0; phase < 2; ++phase) {
            if (active) {
                #pragma unroll
                for (int ddl = 0; ddl < 2; ++ddl) {
                    const int dd = phase * 2 + ddl;
                    f32x4 o;
                    o.x = acc[dd][0] * 0.125f;
                    o.y = acc[dd][1] * 0.125f;
                    o.z = acc[dd][2] * 0.125f;
                    o.w = acc[dd][3] * 0.125f;
                    wb[ddl][wv][t] = o;
                }
            }
            asm volatile("s_waitcnt lgkmcnt(0)" ::: "memory");
            __builtin_amdgcn_s_barrier();
            __builtin_amdgcn_sched_barrier(0);

            // Cooperative dense store: 960 f32x4 (2 slices x 8 rows x 960B),
            // tid-linear -> full 1024B-aligned 64-lane nt bursts.
            const int d_base = dg * 4 + phase * 2;
            const size_t cbase = chunk00 + (size_t)d_base * HW;  // floats
            {
                const int f   = tid;                 // 0..511
                const int ddl = f / 480;
                const int rem = f - ddl * 480;
                const f32x4 v = wbflat[f];
                __builtin_nontemporal_store(
                    v, reinterpret_cast<f32x4*>(out + cbase + (size_t)ddl * HW + 4 * rem));
            }
            if (tid < 960 - 512) {                   // second sweep: f = tid+512
                const int f   = tid + 512;           // 512..959 -> ddl=1
                const int rem = f - 480;
                const f32x4 v = wbflat[f];
                __builtin_nontemporal_store(
                    v, reinterpret_cast<f32x4*>(out + cbase + (size_t)HW + 4 * rem));
            }

            asm volatile("s_waitcnt lgkmcnt(0)" ::: "memory");
            __builtin_amdgcn_s_barrier();            // wb reusable next phase
            __builtin_amdgcn_sched_barrier(0);
        }
    }
}

extern "C" void kernel_launch(void* const* d_in, const int* in_sizes, int n_in,
                              void* d_out, int out_size, void* d_ws, size_t ws_size,
                              hipStream_t stream) {
    const float* left  = (const float*)d_in[0];
    const float* right = (const float*)d_in[1];
    float* out = (float*)d_out;

    dim3 grid(NBLK);                    // 1280 blocks
    dim3 block(512);                    // 8 waves, 8 consecutive h rows of one (b,g)
    hipLaunchKernelGGL(gwc_volume_kernel, grid, block, 0, stream,
                       left, right, out);
}